// Round 1
// baseline (1740.584 us; speedup 1.0000x reference)
//
#include <hip/hip_runtime.h>
#include <math.h>

#define MUL_IN 8
#define MUL_OUT 16
#define HD 64
#define SQ3 1.7320508075688772f

// d_ws layout: W2T[128][4][64] floats  (= 32768 floats = 128 KiB)
// W2T[(u*16+wq)*256 + path*64 + j] = W2[j*512 + path*128 + u*16 + wq] * scale
// scale = 1/32 (= 1/sqrt(64) * 1/sqrt(2*MUL_IN)), extra sqrt(3) folded into path C.

__global__ __launch_bounds__(256) void prep_w2(const float* __restrict__ W2,
                                               float* __restrict__ W2T) {
    int t = blockIdx.x * 256 + threadIdx.x;
    if (t >= 4 * MUL_IN * MUL_OUT * HD) return;  // 32768
    int j = t & 63;
    int path = (t >> 6) & 3;
    int uw = t >> 8;            // u*16 + wq, 0..127
    int u = uw >> 4, wq = uw & 15;
    int col = path * 128 + u * 16 + wq;
    float scale = 0.03125f * (path == 2 ? SQ3 : 1.0f);
    W2T[t] = W2[j * 512 + col] * scale;
}

__global__ __launch_bounds__(256) void edge_kernel(
    const float* __restrict__ x, const float* __restrict__ pos,
    const int* __restrict__ ei, const float* __restrict__ W1,
    const float* __restrict__ W2T, float* __restrict__ accum, int E)
{
    __shared__ float feat[256][33];   // 32 features + 1 pad -> (lane+idx)%32 banks
    int e = blockIdx.x * 256 + threadIdx.x;
    if (e >= E) return;
    int src = ei[e];
    int dst = ei[E + e];

    float ex = pos[dst * 3 + 0] - pos[src * 3 + 0];
    float ey = pos[dst * 3 + 1] - pos[src * 3 + 1];
    float ez = pos[dst * 3 + 2] - pos[src * 3 + 2];
    float len = sqrtf(ex * ex + ey * ey + ez * ez);
    len = fmaxf(len, 1e-8f);
    float inv = 1.0f / len;
    float dx = ex * inv, dy = ey * inv, dz = ez * inv;

    // stage this edge's source-node features in LDS (own row, no sync needed)
    const float* xr = x + (size_t)src * 32;
    #pragma unroll
    for (int q = 0; q < 8; ++q) {
        float4 v = *reinterpret_cast<const float4*>(xr + q * 4);
        feat[threadIdx.x][q * 4 + 0] = v.x;
        feat[threadIdx.x][q * 4 + 1] = v.y;
        feat[threadIdx.x][q * 4 + 2] = v.z;
        feat[threadIdx.x][q * 4 + 3] = v.w;
    }

    // hidden layer: h[j] = silu(len * W1[j])
    float h[64];
    #pragma unroll
    for (int j = 0; j < 64; ++j) {
        float z = len * W1[j];
        h[j] = z / (1.0f + __expf(-z));
    }

    float ms[16], cw[16], mv[48];
    #pragma unroll
    for (int q = 0; q < 16; ++q) { ms[q] = 0.f; cw[q] = 0.f; }
    #pragma unroll
    for (int q = 0; q < 48; ++q) mv[q] = 0.f;

    for (int u = 0; u < 8; ++u) {   // rolled: features via LDS (runtime index ok)
        float xs_u = feat[threadIdx.x][u];
        float xv0 = feat[threadIdx.x][8 + u * 3 + 0];
        float xv1 = feat[threadIdx.x][8 + u * 3 + 1];
        float xv2 = feat[threadIdx.x][8 + u * 3 + 2];
        float dot_u = xv0 * dx + xv1 * dy + xv2 * dz;
        const float* rbase = W2T + (size_t)u * 16 * 256;
        #pragma unroll
        for (int wq = 0; wq < 16; ++wq) {
            const float* r = rbase + wq * 256;   // wave-uniform -> scalar loads
            float wa = 0.f, wb = 0.f, wc = 0.f, wd = 0.f;
            #pragma unroll
            for (int j = 0; j < 64; ++j) {
                float hj = h[j];
                wa += hj * r[j];
                wb += hj * r[64 + j];
                wc += hj * r[128 + j];
                wd += hj * r[192 + j];
            }
            ms[wq] += xs_u * wa + dot_u * wb;
            cw[wq] += xs_u * wc;          // path C coefficient (sqrt3 pre-folded)
            mv[wq * 3 + 0] += xv0 * wd;
            mv[wq * 3 + 1] += xv1 * wd;
            mv[wq * 3 + 2] += xv2 * wd;
        }
    }
    // path C outer product with direction
    #pragma unroll
    for (int wq = 0; wq < 16; ++wq) {
        mv[wq * 3 + 0] += cw[wq] * dx;
        mv[wq * 3 + 1] += cw[wq] * dy;
        mv[wq * 3 + 2] += cw[wq] * dz;
    }

    float* o = accum + (size_t)dst * 64;
    #pragma unroll
    for (int c = 0; c < 16; ++c) atomicAdd(o + c, ms[c]);
    #pragma unroll
    for (int c = 0; c < 48; ++c) atomicAdd(o + 16 + c, mv[c]);
}

__global__ __launch_bounds__(256) void node_kernel(
    float* __restrict__ out, const float* __restrict__ Ws,
    const float* __restrict__ Wns, const float* __restrict__ Wg, int N)
{
    int n = blockIdx.x * 256 + threadIdx.x;
    if (n >= N) return;
    float* row = out + (size_t)n * 64;

    float os[16], ov[48];
    #pragma unroll
    for (int q = 0; q < 4; ++q) {
        float4 v = *reinterpret_cast<const float4*>(row + q * 4);
        os[q * 4 + 0] = v.x; os[q * 4 + 1] = v.y;
        os[q * 4 + 2] = v.z; os[q * 4 + 3] = v.w;
    }
    #pragma unroll
    for (int q = 0; q < 12; ++q) {
        float4 v = *reinterpret_cast<const float4*>(row + 16 + q * 4);
        ov[q * 4 + 0] = v.x; ov[q * 4 + 1] = v.y;
        ov[q * 4 + 2] = v.z; ov[q * 4 + 3] = v.w;
    }

    float sres[16], gres[16];
    #pragma unroll
    for (int w = 0; w < 16; ++w) {
        float a = 0.f, b = 0.f;
        #pragma unroll
        for (int u = 0; u < 16; ++u) {
            float o_u = os[u];
            a += o_u * Ws[u * 16 + w];
            b += o_u * Wg[u * 16 + w];
        }
        a *= 0.25f; b *= 0.25f;
        sres[w] = a / (1.0f + __expf(-a));       // silu
        gres[w] = 1.0f / (1.0f + __expf(-b));    // sigmoid
    }

    float gated[48];
    #pragma unroll
    for (int w = 0; w < 16; ++w) {
        float n0 = 0.f, n1 = 0.f, n2 = 0.f;
        #pragma unroll
        for (int u = 0; u < 16; ++u) {
            float wn = Wns[u * 16 + w];
            n0 += ov[u * 3 + 0] * wn;
            n1 += ov[u * 3 + 1] * wn;
            n2 += ov[u * 3 + 2] * wn;
        }
        float gw = gres[w] * 0.25f;
        gated[w * 3 + 0] = n0 * gw;
        gated[w * 3 + 1] = n1 * gw;
        gated[w * 3 + 2] = n2 * gw;
    }

    // write back in place (this thread owns the whole row)
    #pragma unroll
    for (int q = 0; q < 4; ++q) {
        float4 v = make_float4(sres[q * 4 + 0], sres[q * 4 + 1],
                               sres[q * 4 + 2], sres[q * 4 + 3]);
        *reinterpret_cast<float4*>(row + q * 4) = v;
    }
    #pragma unroll
    for (int q = 0; q < 12; ++q) {
        float4 v = make_float4(gated[q * 4 + 0], gated[q * 4 + 1],
                               gated[q * 4 + 2], gated[q * 4 + 3]);
        *reinterpret_cast<float4*>(row + 16 + q * 4) = v;
    }
}

extern "C" void kernel_launch(void* const* d_in, const int* in_sizes, int n_in,
                              void* d_out, int out_size, void* d_ws, size_t ws_size,
                              hipStream_t stream) {
    const float* x   = (const float*)d_in[0];
    const float* pos = (const float*)d_in[1];
    const int*   ei  = (const int*)d_in[2];
    const float* W1  = (const float*)d_in[3];
    const float* W2  = (const float*)d_in[4];
    const float* Ws  = (const float*)d_in[5];
    const float* Wns = (const float*)d_in[6];
    const float* Wg  = (const float*)d_in[7];

    int N = in_sizes[0] / 32;
    int E = in_sizes[2] / 2;
    float* out = (float*)d_out;
    float* W2T = (float*)d_ws;

    hipMemsetAsync(d_out, 0, (size_t)N * 64 * sizeof(float), stream);
    prep_w2<<<128, 256, 0, stream>>>(W2, W2T);
    edge_kernel<<<(E + 255) / 256, 256, 0, stream>>>(x, pos, ei, W1, W2T, out, E);
    node_kernel<<<(N + 255) / 256, 256, 0, stream>>>(out, Ws, Wns, Wg, N);
}

// Round 2
// 121.432 us; speedup vs baseline: 14.3338x; 14.3338x over previous
//
#include <hip/hip_runtime.h>
#include <math.h>

typedef _Float16 half8 __attribute__((ext_vector_type(8)));
typedef float floatx4 __attribute__((ext_vector_type(4)));

#define SQ3 1.7320508075688772f

// bw layout: [path(4)][t(8)][s(2)][lane(64)][elem(8)] _Float16  (32768 = 64 KiB)
// bw value = W2[k][col] * scale, k = s*32 + (lane>>4)*8 + elem,
// col = path*128 + t*16 + (lane&15), scale = 1/32 (sqrt3 folded into path C)
__global__ __launch_bounds__(256) void prep_w2(const float* __restrict__ W2,
                                               _Float16* __restrict__ bw) {
    int t = blockIdx.x * 256 + threadIdx.x;
    if (t >= 32768) return;
    int i    = t & 7;
    int l    = (t >> 3) & 63;
    int s    = (t >> 9) & 1;
    int tt   = (t >> 10) & 7;
    int path = t >> 13;
    int k   = s * 32 + (l >> 4) * 8 + i;
    int col = path * 128 + tt * 16 + (l & 15);
    float scale = 0.03125f * (path == 2 ? SQ3 : 1.0f);
    bw[t] = (_Float16)(W2[k * 512 + col] * scale);
}

__global__ __launch_bounds__(256) void edge_kernel(
    const float* __restrict__ x, const float* __restrict__ pos,
    const int* __restrict__ ei, const float* __restrict__ W1,
    const _Float16* __restrict__ bw, float* __restrict__ out,
    int E, int ntiles)
{
    __shared__ float sW1[64];
    __shared__ float s_len[16];
    __shared__ float s_dir[16][3];
    __shared__ int   s_src[16];
    __shared__ int   s_dst[16];
    __shared__ __align__(16) float s_xs[16][8];
    __shared__ __align__(16) float s_xv[16][24];     // [e][u*3+i]
    __shared__ __align__(16) _Float16 s_hA[2][64][8]; // A-frag layout
    __shared__ float s_ms[2][16][16];                 // path A / B partials
    __shared__ float s_mv[2][16][48];                 // path C / D partials

    const int tid  = threadIdx.x;
    const int wave = tid >> 6;     // 0..3 == path A,B,C,D
    const int lane = tid & 63;

    if (tid < 64) sW1[tid] = W1[tid];

    // register-resident B fragments for this wave's path (16 frags = 64 VGPR)
    half8 bfrag[8][2];
    {
        const half8* bsrc = (const half8*)bw;
        #pragma unroll
        for (int t = 0; t < 8; ++t)
            #pragma unroll
            for (int s = 0; s < 2; ++s)
                bfrag[t][s] = bsrc[(size_t)wave * 1024 + (t * 2 + s) * 64 + lane];
    }

    for (int tile = blockIdx.x; tile < ntiles; tile += gridDim.x) {
        const int ebase = tile * 16;
        __syncthreads();   // protect LDS from previous tile's readers

        // ---- stage 1: per-edge geometry (16 threads) ----
        if (tid < 16) {
            int eg = ebase + tid;
            int ec = (eg < E) ? eg : (E - 1);
            int si = ei[ec];
            int di = ei[E + ec];
            s_src[tid] = si;
            s_dst[tid] = di;
            float ex = pos[di * 3 + 0] - pos[si * 3 + 0];
            float ey = pos[di * 3 + 1] - pos[si * 3 + 1];
            float ez = pos[di * 3 + 2] - pos[si * 3 + 2];
            float len = sqrtf(ex * ex + ey * ey + ez * ez);
            len = fmaxf(len, 1e-8f);
            float inv = 1.0f / len;
            s_len[tid] = len;
            s_dir[tid][0] = ex * inv;
            s_dir[tid][1] = ey * inv;
            s_dir[tid][2] = ez * inv;
        }
        __syncthreads();

        // ---- stage 2: gather x rows (128 thr) + build h A-frags (all thr) ----
        if (tid < 128) {
            int e = tid >> 3, q = tid & 7;
            float4 v = *reinterpret_cast<const float4*>(
                x + (size_t)s_src[e] * 32 + q * 4);
            if (q < 2) {
                s_xs[e][q * 4 + 0] = v.x; s_xs[e][q * 4 + 1] = v.y;
                s_xs[e][q * 4 + 2] = v.z; s_xs[e][q * 4 + 3] = v.w;
            } else {
                int b = (q - 2) * 4;
                s_xv[e][b + 0] = v.x; s_xv[e][b + 1] = v.y;
                s_xv[e][b + 2] = v.z; s_xv[e][b + 3] = v.w;
            }
        }
        {
            int slot = tid >> 1;          // 0..127 = (s,l)
            int s = slot >> 6;
            int l = slot & 63;
            int e = l & 15;
            int half4 = (tid & 1) * 4;    // which 4 of the lane's 8 elems
            int jb = s * 32 + (l >> 4) * 8 + half4;
            float len = s_len[e];
            #pragma unroll
            for (int i = 0; i < 4; ++i) {
                float z = len * sW1[jb + i];
                float h = z / (1.0f + __expf(-z));
                s_hA[s][l][half4 + i] = (_Float16)h;
            }
        }
        __syncthreads();

        // ---- stage 3: MFMA (16 per wave) + path-specific epilogue ----
        half8 a0 = *(const half8*)&s_hA[0][lane][0];
        half8 a1 = *(const half8*)&s_hA[1][lane][0];
        floatx4 acc[8];
        #pragma unroll
        for (int t = 0; t < 8; ++t) {
            floatx4 z = {0.f, 0.f, 0.f, 0.f};
            z = __builtin_amdgcn_mfma_f32_16x16x32_f16(a0, bfrag[t][0], z, 0, 0, 0);
            acc[t] = __builtin_amdgcn_mfma_f32_16x16x32_f16(a1, bfrag[t][1], z, 0, 0, 0);
        }

        const int wp = lane & 15;            // output col w'
        const int er0 = (lane >> 4) * 4;     // first edge row of this lane

        if (wave == 0) {                     // path A: ms += xs.wA
            #pragma unroll
            for (int r = 0; r < 4; ++r) {
                int e = er0 + r;
                float xss[8];
                #pragma unroll
                for (int q = 0; q < 2; ++q) {
                    float4 v = *(const float4*)&s_xs[e][q * 4];
                    xss[q*4+0]=v.x; xss[q*4+1]=v.y; xss[q*4+2]=v.z; xss[q*4+3]=v.w;
                }
                float m = 0.f;
                #pragma unroll
                for (int u = 0; u < 8; ++u) m += xss[u] * acc[u][r];
                s_ms[0][e][wp] = m;
            }
        } else if (wave == 1) {              // path B: ms += (xv.dir).wB
            #pragma unroll
            for (int r = 0; r < 4; ++r) {
                int e = er0 + r;
                float xvv[24];
                #pragma unroll
                for (int q = 0; q < 6; ++q) {
                    float4 v = *(const float4*)&s_xv[e][q * 4];
                    xvv[q*4+0]=v.x; xvv[q*4+1]=v.y; xvv[q*4+2]=v.z; xvv[q*4+3]=v.w;
                }
                float d0 = s_dir[e][0], d1 = s_dir[e][1], d2 = s_dir[e][2];
                float m = 0.f;
                #pragma unroll
                for (int u = 0; u < 8; ++u) {
                    float dot = xvv[u*3+0]*d0 + xvv[u*3+1]*d1 + xvv[u*3+2]*d2;
                    m += dot * acc[u][r];
                }
                s_ms[1][e][wp] = m;
            }
        } else if (wave == 2) {              // path C: mv += (xs.wC) * sqrt3*dir
            #pragma unroll
            for (int r = 0; r < 4; ++r) {
                int e = er0 + r;
                float xss[8];
                #pragma unroll
                for (int q = 0; q < 2; ++q) {
                    float4 v = *(const float4*)&s_xs[e][q * 4];
                    xss[q*4+0]=v.x; xss[q*4+1]=v.y; xss[q*4+2]=v.z; xss[q*4+3]=v.w;
                }
                float cw = 0.f;
                #pragma unroll
                for (int u = 0; u < 8; ++u) cw += xss[u] * acc[u][r];
                s_mv[0][e][wp * 3 + 0] = cw * s_dir[e][0];
                s_mv[0][e][wp * 3 + 1] = cw * s_dir[e][1];
                s_mv[0][e][wp * 3 + 2] = cw * s_dir[e][2];
            }
        } else {                             // path D: mv += xv.wD
            #pragma unroll
            for (int r = 0; r < 4; ++r) {
                int e = er0 + r;
                float xvv[24];
                #pragma unroll
                for (int q = 0; q < 6; ++q) {
                    float4 v = *(const float4*)&s_xv[e][q * 4];
                    xvv[q*4+0]=v.x; xvv[q*4+1]=v.y; xvv[q*4+2]=v.z; xvv[q*4+3]=v.w;
                }
                float m0 = 0.f, m1 = 0.f, m2 = 0.f;
                #pragma unroll
                for (int u = 0; u < 8; ++u) {
                    float w = acc[u][r];
                    m0 += xvv[u*3+0] * w;
                    m1 += xvv[u*3+1] * w;
                    m2 += xvv[u*3+2] * w;
                }
                s_mv[1][e][wp * 3 + 0] = m0;
                s_mv[1][e][wp * 3 + 1] = m1;
                s_mv[1][e][wp * 3 + 2] = m2;
            }
        }
        __syncthreads();

        // ---- stage 4: combined coalesced atomic scatter (1024 values) ----
        {
            int c  = tid & 63;
            int g  = tid >> 6;
            #pragma unroll
            for (int k = 0; k < 4; ++k) {
                int e  = g * 4 + k;
                int eg = ebase + e;
                if (eg < E) {
                    float v;
                    if (c < 16) v = s_ms[0][e][c] + s_ms[1][e][c];
                    else        v = s_mv[0][e][c - 16] + s_mv[1][e][c - 16];
                    atomicAdd(out + (size_t)s_dst[e] * 64 + c, v);
                }
            }
        }
    }
}

__global__ __launch_bounds__(256) void node_kernel(
    float* __restrict__ out, const float* __restrict__ Ws,
    const float* __restrict__ Wns, const float* __restrict__ Wg, int N)
{
    int n = blockIdx.x * 256 + threadIdx.x;
    if (n >= N) return;
    float* row = out + (size_t)n * 64;

    float os[16], ov[48];
    #pragma unroll
    for (int q = 0; q < 4; ++q) {
        float4 v = *reinterpret_cast<const float4*>(row + q * 4);
        os[q*4+0]=v.x; os[q*4+1]=v.y; os[q*4+2]=v.z; os[q*4+3]=v.w;
    }
    #pragma unroll
    for (int q = 0; q < 12; ++q) {
        float4 v = *reinterpret_cast<const float4*>(row + 16 + q * 4);
        ov[q*4+0]=v.x; ov[q*4+1]=v.y; ov[q*4+2]=v.z; ov[q*4+3]=v.w;
    }

    float sres[16], gres[16];
    #pragma unroll
    for (int w = 0; w < 16; ++w) {
        float a = 0.f, b = 0.f;
        #pragma unroll
        for (int u = 0; u < 16; ++u) {
            float o_u = os[u];
            a += o_u * Ws[u * 16 + w];
            b += o_u * Wg[u * 16 + w];
        }
        a *= 0.25f; b *= 0.25f;
        sres[w] = a / (1.0f + __expf(-a));
        gres[w] = 1.0f / (1.0f + __expf(-b));
    }

    float gated[48];
    #pragma unroll
    for (int w = 0; w < 16; ++w) {
        float n0 = 0.f, n1 = 0.f, n2 = 0.f;
        #pragma unroll
        for (int u = 0; u < 16; ++u) {
            float wn = Wns[u * 16 + w];
            n0 += ov[u*3+0] * wn;
            n1 += ov[u*3+1] * wn;
            n2 += ov[u*3+2] * wn;
        }
        float gw = gres[w] * 0.25f;
        gated[w*3+0] = n0 * gw;
        gated[w*3+1] = n1 * gw;
        gated[w*3+2] = n2 * gw;
    }

    #pragma unroll
    for (int q = 0; q < 4; ++q) {
        float4 v = make_float4(sres[q*4+0], sres[q*4+1], sres[q*4+2], sres[q*4+3]);
        *reinterpret_cast<float4*>(row + q * 4) = v;
    }
    #pragma unroll
    for (int q = 0; q < 12; ++q) {
        float4 v = make_float4(gated[q*4+0], gated[q*4+1], gated[q*4+2], gated[q*4+3]);
        *reinterpret_cast<float4*>(row + 16 + q * 4) = v;
    }
}

extern "C" void kernel_launch(void* const* d_in, const int* in_sizes, int n_in,
                              void* d_out, int out_size, void* d_ws, size_t ws_size,
                              hipStream_t stream) {
    const float* x   = (const float*)d_in[0];
    const float* pos = (const float*)d_in[1];
    const int*   ei  = (const int*)d_in[2];
    const float* W1  = (const float*)d_in[3];
    const float* W2  = (const float*)d_in[4];
    const float* Ws  = (const float*)d_in[5];
    const float* Wns = (const float*)d_in[6];
    const float* Wg  = (const float*)d_in[7];

    int N = in_sizes[0] / 32;
    int E = in_sizes[2] / 2;
    int ntiles = (E + 15) / 16;
    float* out = (float*)d_out;
    _Float16* bw = (_Float16*)d_ws;

    hipMemsetAsync(d_out, 0, (size_t)N * 64 * sizeof(float), stream);
    prep_w2<<<128, 256, 0, stream>>>(W2, bw);
    int nblk = ntiles < 1536 ? ntiles : 1536;
    edge_kernel<<<nblk, 256, 0, stream>>>(x, pos, ei, W1, bw, out, E, ntiles);
    node_kernel<<<(N + 255) / 256, 256, 0, stream>>>(out, Ws, Wns, Wg, N);
}